// Round 15
// baseline (28.273 us; speedup 1.0000x reference)
//
#include <hip/hip_runtime.h>

typedef _Float16 f16;
typedef __attribute__((ext_vector_type(2))) _Float16 f16x2;
typedef __attribute__((ext_vector_type(4))) _Float16 f16x4;
typedef __attribute__((ext_vector_type(8))) _Float16 f16x8;
typedef __attribute__((ext_vector_type(4))) float f32x4;
typedef __attribute__((ext_vector_type(4))) unsigned u32x4;

constexpr int IN_F  = 4096;
constexpr int OUT_F = 11008;
constexpr int NGRP  = 32;     // 4096 / 128
constexpr int NTILE = OUT_F / 16;          // 688
constexpr int PLANE = OUT_F * 8;           // 88064 floats per split-K partial plane

// dequant one byte-holding int32 (2 nibbles) -> 2 packed f16 weights
__device__ __forceinline__ unsigned dq2(unsigned q, f16x2 sp, f16x2 zp) {
    unsigned t = (((q << 12) | q) & 0x000F000Fu) | 0x64006400u;  // (1024+lo, 1024+hi)
    f16x2 u = __builtin_bit_cast(f16x2, t);
    u = u - (f16x2){(_Float16)1024.0f, (_Float16)1024.0f};       // exact
    u = u * sp + zp;                                             // v_pk_fma_f16
    return __builtin_bit_cast(unsigned, u);
}

__device__ __forceinline__ f16x2 bcast(float v) {
    _Float16 h = (_Float16)v;
    return (f16x2){h, h};
}

// x [8][4096] fp32 -> f16 workspace (halves x vmem traffic in main kernel)
__global__ void xprep_kernel(const float* __restrict__ x, f16* __restrict__ xh) {
    int i = (blockIdx.x * blockDim.x + threadIdx.x) * 4;
    float4 v = *(const float4*)(x + i);
    f16x4 r = {(f16)v.x, (f16)v.y, (f16)v.z, (f16)v.w};
    *(f16x4*)(xh + i) = r;
}

// R8 structure, single delta: x loads are f16 (8x f16x8 instead of 16x float4).
// Vmem-path aggregate drops 178 -> 134 MB. Everything else byte-identical:
// 2752 blocks (688 o-tiles x 4 split-K) x 4 waves, 8 gload_lds/wave (2 rows x
// 512B, src XOR-swizzled), one vmcnt(0), 8 MFMA, cross-wave reduce, f32
// partials to plane[kq]; reduce kernel adds bias + 4 planes.
__global__ __launch_bounds__(256, 4)
void qlin_partial(const int* __restrict__ wq,
                  const float* __restrict__ scales,
                  const float* __restrict__ zeros,
                  const f16* __restrict__ xh,
                  float* __restrict__ wsf)
{
    __shared__ unsigned char wlds[4][8192];   // 8KB per wave
    __shared__ f32x4 red[4][64];

    const int tid  = threadIdx.x;
    const int wv   = tid >> 6;
    const int lane = tid & 63;
    const int col  = lane & 15;      // B col n = weight row; A row m
    const int kg   = lane >> 4;
    const int bid  = blockIdx.x;
    const int kq   = bid & 3;        // split-K quarter
    const int ot   = bid >> 2;       // o-tile
    const int o0   = ot * 16;
    const int orow = o0 + col;
    const bool mvalid = (col < 8);

    const int k0 = kq * 1024 + wv * 256;     // this wave's k start (2 groups)
    const int g0 = k0 >> 7;

    const f16x2 sp0 = bcast(scales[(size_t)orow * NGRP + g0]);
    const f16x2 sp1 = bcast(scales[(size_t)orow * NGRP + g0 + 1]);
    const f16x2 zp0 = bcast(zeros [(size_t)orow * NGRP + g0]);
    const f16x2 zp1 = bcast(zeros [(size_t)orow * NGRP + g0 + 1]);

    // ---- burst: stage 8KB of weights (8 insts, 2 rows x 512B each) ----
    const char* wb = (const char*)wq;
    #pragma unroll
    for (int c = 0; c < 8; ++c) {
        const int r    = 2 * c + (lane >> 5);          // row within tile
        const size_t grow = (size_t)(o0 + r);
        const char* src = wb + grow * 8192 + (size_t)k0 * 2
                          + (((lane & 31) * 16) ^ ((r & 7) << 4));
        __builtin_amdgcn_global_load_lds(
            (const __attribute__((address_space(1))) void*)src,
            (__attribute__((address_space(3))) void*)&wlds[wv][c * 1024],
            16, 0, 0);
    }

    // ---- burst: x loads (f16), this lane's 8 k's per k-tile t=0..7 ----
    f16x8 af[8];
    if (mvalid) {
        const f16* xp = xh + (size_t)col * IN_F + k0 + kg * 8;
        #pragma unroll
        for (int t = 0; t < 8; ++t)
            af[t] = *(const f16x8*)(xp + t * 32);
    } else {
        #pragma unroll
        for (int t = 0; t < 8; ++t)
            af[t] = (f16x8){0,0,0,0,0,0,0,0};
    }

    asm volatile("s_waitcnt vmcnt(0)" ::: "memory");
    __builtin_amdgcn_sched_barrier(0);

    // ---- compute: 8 k-tiles of 32, groups split at t=4 ----
    const unsigned swz  = (unsigned)((col & 7) << 4);
    const unsigned base = (unsigned)(wv * 8192 + col * 512);
    const unsigned char* lf = &wlds[0][0];

    f32x4 acc = {0.f, 0.f, 0.f, 0.f};
    #pragma unroll
    for (int t = 0; t < 8; ++t) {
        const unsigned off = base + (((unsigned)(t * 64 + kg * 16)) ^ swz);
        const int4 q = *(const int4*)(lf + off);
        const f16x2 s2 = (t < 4) ? sp0 : sp1;
        const f16x2 z2 = (t < 4) ? zp0 : zp1;
        u32x4 bw = {dq2((unsigned)q.x, s2, z2),
                    dq2((unsigned)q.y, s2, z2),
                    dq2((unsigned)q.z, s2, z2),
                    dq2((unsigned)q.w, s2, z2)};
        f16x8 bfr = __builtin_bit_cast(f16x8, bw);
        acc = __builtin_amdgcn_mfma_f32_16x16x32_f16(af[t], bfr, acc, 0, 0, 0);
    }

    // ---- cross-wave reduce (the only barrier) + partial write ----
    red[wv][lane] = acc;
    __syncthreads();

    if (tid < 64) {
        f32x4 ssum = red[0][tid];
        #pragma unroll
        for (int w = 1; w < 4; ++w) ssum += red[w][tid];
        const int n = tid & 15;
        const int mbase = (tid >> 4) * 4;   // C/D row = (lane>>4)*4 + reg
        if (mbase < 8) {
            float* plane = wsf + (size_t)kq * PLANE;
            #pragma unroll
            for (int i = 0; i < 4; ++i)
                plane[(size_t)(mbase + i) * OUT_F + o0 + n] = ssum[i];
        }
    }
}

// out[idx] = bias[o] + sum of 4 split-K planes
__global__ __launch_bounds__(256)
void reduce_kernel(const float* __restrict__ wsf,
                   const float* __restrict__ bias,
                   float* __restrict__ out)
{
    const int idx = blockIdx.x * 256 + threadIdx.x;   // 0..88063
    const int o = idx % OUT_F;
    out[idx] = bias[o] + wsf[idx] + wsf[PLANE + idx]
             + wsf[2 * PLANE + idx] + wsf[3 * PLANE + idx];
}

// ---------------- fallback (R5 kernel, used only if ws too small) ----------
__global__ __launch_bounds__(256, 4)
void qlin_kernel(const int* __restrict__ wq,
                 const float* __restrict__ scales,
                 const float* __restrict__ zeros,
                 const float* __restrict__ bias,
                 const float* __restrict__ xf,
                 float* __restrict__ out)
{
    __shared__ unsigned char wlds[2][16][1024];
    __shared__ f32x4 red[4][64];

    const int tid  = threadIdx.x;
    const int wv   = tid >> 6;
    const int lane = tid & 63;
    const int col  = lane & 15;
    const int kg   = lane >> 4;
    const int o0   = blockIdx.x * 16;
    const int orow = o0 + col;
    const bool mvalid = (col < 8);

    f16x2 sp[8], zp[8];
    #pragma unroll
    for (int s = 0; s < 8; ++s) {
        sp[s] = bcast(scales[(size_t)orow * NGRP + s * 4 + wv]);
        zp[s] = bcast(zeros [(size_t)orow * NGRP + s * 4 + wv]);
    }

    const char* wtile = (const char*)wq + (size_t)o0 * 8192;
    auto stage = [&](int sl, int bufi) {
        #pragma unroll
        for (int c = 0; c < 4; ++c) {
            const int r = 4 * wv + c;
            const char* src = wtile + (size_t)r * 8192 + sl * 1024
                              + ((lane * 16) ^ ((r & 7) << 4));
            __builtin_amdgcn_global_load_lds(
                (const __attribute__((address_space(1))) void*)src,
                (__attribute__((address_space(3))) void*)&wlds[bufi][r][0],
                16, 0, 0);
        }
    };

    stage(0, 0);
    stage(1, 1);

    const float* xfcol = xf + (size_t)col * IN_F;
    const unsigned swz = (unsigned)((col & 7) << 4);
    f32x4 acc = {0.f, 0.f, 0.f, 0.f};

    #pragma unroll
    for (int s = 0; s < 8; ++s) {
        asm volatile("s_waitcnt vmcnt(0)" ::: "memory");
        __builtin_amdgcn_s_barrier();
        asm volatile("" ::: "memory");

        const f16x2 s2 = sp[s], z2 = zp[s];
        #pragma unroll
        for (int t = 0; t < 4; ++t) {
            const int k = s * 512 + wv * 128 + t * 32 + kg * 8;
            f16x8 af = (f16x8){0,0,0,0,0,0,0,0};
            if (mvalid) {
                float4 a0 = *(const float4*)(xfcol + k);
                float4 a1 = *(const float4*)(xfcol + k + 4);
                af = (f16x8){(f16)a0.x,(f16)a0.y,(f16)a0.z,(f16)a0.w,
                             (f16)a1.x,(f16)a1.y,(f16)a1.z,(f16)a1.w};
            }
            const unsigned off = ((unsigned)(wv * 256 + t * 64 + kg * 16)) ^ swz;
            const int4 q = *(const int4*)&wlds[s & 1][col][off];
            u32x4 bw = {dq2((unsigned)q.x, s2, z2),
                        dq2((unsigned)q.y, s2, z2),
                        dq2((unsigned)q.z, s2, z2),
                        dq2((unsigned)q.w, s2, z2)};
            f16x8 bfr = __builtin_bit_cast(f16x8, bw);
            acc = __builtin_amdgcn_mfma_f32_16x16x32_f16(af, bfr, acc, 0, 0, 0);
        }

        asm volatile("" ::: "memory");
        __builtin_amdgcn_s_barrier();
        if (s < 6) stage(s + 2, s & 1);
    }

    red[wv][lane] = acc;
    __syncthreads();

    if (tid < 64) {
        f32x4 ssum = red[0][tid];
        #pragma unroll
        for (int w = 1; w < 4; ++w) ssum += red[w][tid];
        const int n = tid & 15;
        const float bb = bias[o0 + n];
        const int mbase = (tid >> 4) * 4;
        if (mbase < 8) {
            #pragma unroll
            for (int i = 0; i < 4; ++i)
                out[(size_t)(mbase + i) * OUT_F + o0 + n] = ssum[i] + bb;
        }
    }
}

extern "C" void kernel_launch(void* const* d_in, const int* in_sizes, int n_in,
                              void* d_out, int out_size, void* d_ws, size_t ws_size,
                              hipStream_t stream) {
    const float* x  = (const float*)d_in[0];
    const int*   wq = (const int*)d_in[1];
    const float* sc = (const float*)d_in[2];
    const float* zr = (const float*)d_in[3];
    const float* bs = (const float*)d_in[4];
    float* out = (float*)d_out;
    (void)in_sizes; (void)n_in;

    const size_t planes_b = (size_t)4 * PLANE * sizeof(float);
    const size_t xh_b     = (size_t)8 * IN_F * sizeof(f16);

    if (ws_size >= planes_b + xh_b) {
        float* wsf = (float*)d_ws;
        f16*   xh  = (f16*)((char*)d_ws + planes_b);
        xprep_kernel<<<(8 * IN_F) / (256 * 4), 256, 0, stream>>>(x, xh);
        qlin_partial<<<NTILE * 4, 256, 0, stream>>>(wq, sc, zr, xh, wsf);
        reduce_kernel<<<PLANE / 256, 256, 0, stream>>>(wsf, bs, out);
    } else {
        qlin_kernel<<<NTILE, 256, 0, stream>>>(wq, sc, zr, bs, x, out);
    }
}

// Round 16
// 27.621 us; speedup vs baseline: 1.0236x; 1.0236x over previous
//
#include <hip/hip_runtime.h>

typedef _Float16 f16;
typedef __attribute__((ext_vector_type(2))) _Float16 f16x2;
typedef __attribute__((ext_vector_type(8))) _Float16 f16x8;
typedef __attribute__((ext_vector_type(4))) float f32x4;
typedef __attribute__((ext_vector_type(4))) unsigned u32x4;

constexpr int IN_F  = 4096;
constexpr int OUT_F = 11008;
constexpr int NGRP  = 32;     // 4096 / 128
constexpr int NTILE = OUT_F / 16;          // 688
constexpr int PLANE = OUT_F * 8;           // 88064 floats per split-K partial plane

// dequant one byte-holding int32 (2 nibbles) -> 2 packed f16 weights
__device__ __forceinline__ unsigned dq2(unsigned q, f16x2 sp, f16x2 zp) {
    unsigned t = (((q << 12) | q) & 0x000F000Fu) | 0x64006400u;  // (1024+lo, 1024+hi)
    f16x2 u = __builtin_bit_cast(f16x2, t);
    u = u - (f16x2){(_Float16)1024.0f, (_Float16)1024.0f};       // exact
    u = u * sp + zp;                                             // v_pk_fma_f16
    return __builtin_bit_cast(unsigned, u);
}

__device__ __forceinline__ f16x2 bcast(float v) {
    _Float16 h = (_Float16)v;
    return (f16x2){h, h};
}

// FINAL: R8 best-known kernel (27.66 us, reproduced twice).
// 2752 blocks (688 o-tiles x 4 split-K) x 4 waves. Each wave independent:
// (o-tile, 256-k slice). Burst: 8 global_load_lds (2 rows x 512B each, src
// XOR-swizzled) + 16 f32 x-loads, one vmcnt(0), 8 MFMA, cross-wave reduce,
// f32 partials to ws plane [kq]; reduce kernel adds bias + 4 planes.
__global__ __launch_bounds__(256, 4)
void qlin_partial(const int* __restrict__ wq,
                  const float* __restrict__ scales,
                  const float* __restrict__ zeros,
                  const float* __restrict__ xf,
                  float* __restrict__ wsf)
{
    __shared__ unsigned char wlds[4][8192];   // 8KB per wave
    __shared__ f32x4 red[4][64];

    const int tid  = threadIdx.x;
    const int wv   = tid >> 6;
    const int lane = tid & 63;
    const int col  = lane & 15;      // B col n = weight row; A row m
    const int kg   = lane >> 4;
    const int bid  = blockIdx.x;
    const int kq   = bid & 3;        // split-K quarter
    const int ot   = bid >> 2;       // o-tile
    const int o0   = ot * 16;
    const int orow = o0 + col;
    const bool mvalid = (col < 8);

    const int k0 = kq * 1024 + wv * 256;     // this wave's k start (2 groups)
    const int g0 = k0 >> 7;

    const f16x2 sp0 = bcast(scales[(size_t)orow * NGRP + g0]);
    const f16x2 sp1 = bcast(scales[(size_t)orow * NGRP + g0 + 1]);
    const f16x2 zp0 = bcast(zeros [(size_t)orow * NGRP + g0]);
    const f16x2 zp1 = bcast(zeros [(size_t)orow * NGRP + g0 + 1]);

    // ---- burst: stage 8KB of weights (8 insts, 2 rows x 512B each) ----
    const char* wb = (const char*)wq;
    #pragma unroll
    for (int c = 0; c < 8; ++c) {
        const int r    = 2 * c + (lane >> 5);          // row within tile
        const size_t grow = (size_t)(o0 + r);
        const char* src = wb + grow * 8192 + (size_t)k0 * 2
                          + (((lane & 31) * 16) ^ ((r & 7) << 4));
        __builtin_amdgcn_global_load_lds(
            (const __attribute__((address_space(1))) void*)src,
            (__attribute__((address_space(3))) void*)&wlds[wv][c * 1024],
            16, 0, 0);
    }

    // ---- burst: x loads (f32), this lane's 8 k's per k-tile t=0..7 ----
    float4 xr[16];
    if (mvalid) {
        const float* xp = xf + (size_t)col * IN_F + k0 + kg * 8;
        #pragma unroll
        for (int t = 0; t < 8; ++t) {
            xr[2 * t]     = *(const float4*)(xp + t * 32);
            xr[2 * t + 1] = *(const float4*)(xp + t * 32 + 4);
        }
    } else {
        #pragma unroll
        for (int i = 0; i < 16; ++i) xr[i] = (float4){0.f, 0.f, 0.f, 0.f};
    }

    asm volatile("s_waitcnt vmcnt(0)" ::: "memory");
    __builtin_amdgcn_sched_barrier(0);

    // ---- compute: 8 k-tiles of 32, groups split at t=4 ----
    const unsigned swz  = (unsigned)((col & 7) << 4);
    const unsigned base = (unsigned)(wv * 8192 + col * 512);
    const unsigned char* lf = &wlds[0][0];

    f32x4 acc = {0.f, 0.f, 0.f, 0.f};
    #pragma unroll
    for (int t = 0; t < 8; ++t) {
        f16x8 af = (f16x8){(f16)xr[2*t].x,   (f16)xr[2*t].y,   (f16)xr[2*t].z,   (f16)xr[2*t].w,
                           (f16)xr[2*t+1].x, (f16)xr[2*t+1].y, (f16)xr[2*t+1].z, (f16)xr[2*t+1].w};
        const unsigned off = base + (((unsigned)(t * 64 + kg * 16)) ^ swz);
        const int4 q = *(const int4*)(lf + off);
        const f16x2 s2 = (t < 4) ? sp0 : sp1;
        const f16x2 z2 = (t < 4) ? zp0 : zp1;
        u32x4 bw = {dq2((unsigned)q.x, s2, z2),
                    dq2((unsigned)q.y, s2, z2),
                    dq2((unsigned)q.z, s2, z2),
                    dq2((unsigned)q.w, s2, z2)};
        f16x8 bfr = __builtin_bit_cast(f16x8, bw);
        acc = __builtin_amdgcn_mfma_f32_16x16x32_f16(af, bfr, acc, 0, 0, 0);
    }

    // ---- cross-wave reduce (the only barrier) + partial write ----
    red[wv][lane] = acc;
    __syncthreads();

    if (tid < 64) {
        f32x4 ssum = red[0][tid];
        #pragma unroll
        for (int w = 1; w < 4; ++w) ssum += red[w][tid];
        const int n = tid & 15;
        const int mbase = (tid >> 4) * 4;   // C/D row = (lane>>4)*4 + reg
        if (mbase < 8) {
            float* plane = wsf + (size_t)kq * PLANE;
            #pragma unroll
            for (int i = 0; i < 4; ++i)
                plane[(size_t)(mbase + i) * OUT_F + o0 + n] = ssum[i];
        }
    }
}

// out[idx] = bias[o] + sum of 4 split-K planes
__global__ __launch_bounds__(256)
void reduce_kernel(const float* __restrict__ wsf,
                   const float* __restrict__ bias,
                   float* __restrict__ out)
{
    const int idx = blockIdx.x * 256 + threadIdx.x;   // 0..88063
    const int o = idx % OUT_F;
    out[idx] = bias[o] + wsf[idx] + wsf[PLANE + idx]
             + wsf[2 * PLANE + idx] + wsf[3 * PLANE + idx];
}

// ---------------- fallback (R5 kernel, used only if ws too small) ----------
__global__ __launch_bounds__(256, 4)
void qlin_kernel(const int* __restrict__ wq,
                 const float* __restrict__ scales,
                 const float* __restrict__ zeros,
                 const float* __restrict__ bias,
                 const float* __restrict__ xf,
                 float* __restrict__ out)
{
    __shared__ unsigned char wlds[2][16][1024];
    __shared__ f32x4 red[4][64];

    const int tid  = threadIdx.x;
    const int wv   = tid >> 6;
    const int lane = tid & 63;
    const int col  = lane & 15;
    const int kg   = lane >> 4;
    const int o0   = blockIdx.x * 16;
    const int orow = o0 + col;
    const bool mvalid = (col < 8);

    f16x2 sp[8], zp[8];
    #pragma unroll
    for (int s = 0; s < 8; ++s) {
        sp[s] = bcast(scales[(size_t)orow * NGRP + s * 4 + wv]);
        zp[s] = bcast(zeros [(size_t)orow * NGRP + s * 4 + wv]);
    }

    const char* wtile = (const char*)wq + (size_t)o0 * 8192;
    auto stage = [&](int sl, int bufi) {
        #pragma unroll
        for (int c = 0; c < 4; ++c) {
            const int r = 4 * wv + c;
            const char* src = wtile + (size_t)r * 8192 + sl * 1024
                              + ((lane * 16) ^ ((r & 7) << 4));
            __builtin_amdgcn_global_load_lds(
                (const __attribute__((address_space(1))) void*)src,
                (__attribute__((address_space(3))) void*)&wlds[bufi][r][0],
                16, 0, 0);
        }
    };

    stage(0, 0);
    stage(1, 1);

    const float* xfcol = xf + (size_t)col * IN_F;
    const unsigned swz = (unsigned)((col & 7) << 4);
    f32x4 acc = {0.f, 0.f, 0.f, 0.f};

    #pragma unroll
    for (int s = 0; s < 8; ++s) {
        asm volatile("s_waitcnt vmcnt(0)" ::: "memory");
        __builtin_amdgcn_s_barrier();
        asm volatile("" ::: "memory");

        const f16x2 s2 = sp[s], z2 = zp[s];
        #pragma unroll
        for (int t = 0; t < 4; ++t) {
            const int k = s * 512 + wv * 128 + t * 32 + kg * 8;
            f16x8 af = (f16x8){0,0,0,0,0,0,0,0};
            if (mvalid) {
                float4 a0 = *(const float4*)(xfcol + k);
                float4 a1 = *(const float4*)(xfcol + k + 4);
                af = (f16x8){(f16)a0.x,(f16)a0.y,(f16)a0.z,(f16)a0.w,
                             (f16)a1.x,(f16)a1.y,(f16)a1.z,(f16)a1.w};
            }
            const unsigned off = ((unsigned)(wv * 256 + t * 64 + kg * 16)) ^ swz;
            const int4 q = *(const int4*)&wlds[s & 1][col][off];
            u32x4 bw = {dq2((unsigned)q.x, s2, z2),
                        dq2((unsigned)q.y, s2, z2),
                        dq2((unsigned)q.z, s2, z2),
                        dq2((unsigned)q.w, s2, z2)};
            f16x8 bfr = __builtin_bit_cast(f16x8, bw);
            acc = __builtin_amdgcn_mfma_f32_16x16x32_f16(af, bfr, acc, 0, 0, 0);
        }

        asm volatile("" ::: "memory");
        __builtin_amdgcn_s_barrier();
        if (s < 6) stage(s + 2, s & 1);
    }

    red[wv][lane] = acc;
    __syncthreads();

    if (tid < 64) {
        f32x4 ssum = red[0][tid];
        #pragma unroll
        for (int w = 1; w < 4; ++w) ssum += red[w][tid];
        const int n = tid & 15;
        const float bb = bias[o0 + n];
        const int mbase = (tid >> 4) * 4;
        if (mbase < 8) {
            #pragma unroll
            for (int i = 0; i < 4; ++i)
                out[(size_t)(mbase + i) * OUT_F + o0 + n] = ssum[i] + bb;
        }
    }
}

extern "C" void kernel_launch(void* const* d_in, const int* in_sizes, int n_in,
                              void* d_out, int out_size, void* d_ws, size_t ws_size,
                              hipStream_t stream) {
    const float* x  = (const float*)d_in[0];
    const int*   wq = (const int*)d_in[1];
    const float* sc = (const float*)d_in[2];
    const float* zr = (const float*)d_in[3];
    const float* bs = (const float*)d_in[4];
    float* out = (float*)d_out;
    (void)in_sizes; (void)n_in;

    if (ws_size >= (size_t)4 * PLANE * sizeof(float)) {
        float* wsf = (float*)d_ws;
        qlin_partial<<<NTILE * 4, 256, 0, stream>>>(wq, sc, zr, x, wsf);
        reduce_kernel<<<PLANE / 256, 256, 0, stream>>>(wsf, bs, out);
    } else {
        qlin_kernel<<<NTILE, 256, 0, stream>>>(wq, sc, zr, bs, x, out);
    }
}